// Round 2
// baseline (415.612 us; speedup 1.0000x reference)
//
#include <hip/hip_runtime.h>

// Problem shape (fixed by setup_inputs): left/right [B,C,H,W] fp32,
// out volume [B,C,D,H,W] fp32:
//   out[b,c,d,y,x] = left[b,c,y,x] - right[b,c,y,x-d]  (x>=d, else 0)
#define BB 2
#define CC 32
#define HH 96
#define WW 320
#define DD 48
#define NBC   (BB * CC)          // 64 fused b*C+c slices
#define SLICE (HH * WW)          // 30720 floats per (bc) or (bc,d) slice
#define W4    (WW / 4)           // 80 float4 columns per row
#define RPG   4                  // rows per iteration group (320 thr = 4 x 80)
#define NIT   (HH / RPG)         // 24 iterations cover 96 rows

// One block per (bc, d): the block's entire 122,880 B output slice is
// CONTIGUOUS, so the write stream matches the fillBuffer pattern that
// demonstrably hits 6.2 TB/s on this buffer (vs the previous d-strided
// layout at ~2.6 TB/s effective).
//
// Reads: left/right slices for one bc are re-read by its 48 d-blocks, but
// the swizzle below pins all 48 onto ONE XCD (default round-robin
// dispatch: consecutive blockIdx -> consecutive XCD), so each 240 KB
// slice pair is HBM-fetched once per XCD and L2-hit 47 times
// (8 bc/XCD x 240 KB = 1.9 MB << 4 MB L2). Total HBM reads stay ~16 MB.
//
// Row-group rotation by d staggers the 48 concurrent same-bc readers
// across the slice so cold L2 misses don't all target the same lines at
// t=0 (bounded dup-fetch instead of 48x).
__global__ __launch_bounds__(320) void diffvol_kernel(
        const float* __restrict__ left,
        const float* __restrict__ right,
        float* __restrict__ out) {
    const int bid = blockIdx.x;          // 0..3071
    const int xcd = bid & 7;             // XCD this block lands on
    const int loc = bid >> 3;            // 0..383 within the XCD's share
    const int bc  = xcd * (NBC / 8) + loc / DD;   // 0..63, bijective
    const int d   = loc % DD;            // 0..47

    const int tid = threadIdx.x;         // 0..319
    const int r   = tid / W4;            // 0..3  row within group
    const int c   = tid % W4;            // 0..79 float4 column
    const int x0  = c * 4;

    const float* lslice = left  + bc * SLICE;
    const float* rslice = right + bc * SLICE;
    float*       oslice = out + (bc * DD + d) * SLICE;

    const int g0 = d % NIT;              // per-d rotation (spread L2 misses)
    const int sb = x0 - d;               // source column of element k=0

    for (int it = 0; it < NIT; ++it) {
        int grp = it + g0; if (grp >= NIT) grp -= NIT;
        const int y      = grp * RPG + r;
        const int rowoff = y * WW + x0;  // 16B-aligned (x0 % 4 == 0)

        const float4 l4 = *reinterpret_cast<const float4*>(lslice + rowoff);
        float4 v;
        if (sb >= 0) {
            // Common case (68/80 columns): all four sources in-range.
            const float* rp = rslice + y * WW + sb;
            v.x = l4.x - rp[0];
            v.y = l4.y - rp[1];
            v.z = l4.z - rp[2];
            v.w = l4.w - rp[3];
        } else {
            // Left boundary: per-element validity, clamp the gather index.
            const float* rrow = rslice + y * WW;
            const float lv[4] = {l4.x, l4.y, l4.z, l4.w};
            float t[4];
            #pragma unroll
            for (int k = 0; k < 4; ++k) {
                const int s = sb + k;
                const float rv = rrow[s >= 0 ? s : 0];
                t[k] = (s >= 0) ? lv[k] - rv : 0.0f;
            }
            v.x = t[0]; v.y = t[1]; v.z = t[2]; v.w = t[3];
        }
        *reinterpret_cast<float4*>(oslice + rowoff) = v;
    }
}

extern "C" void kernel_launch(void* const* d_in, const int* in_sizes, int n_in,
                              void* d_out, int out_size, void* d_ws, size_t ws_size,
                              hipStream_t stream) {
    const float* left  = (const float*)d_in[0];
    const float* right = (const float*)d_in[1];
    float* out = (float*)d_out;

    const int grid = NBC * DD;           // 3072 blocks = 12 per CU exactly
    diffvol_kernel<<<grid, 320, 0, stream>>>(left, right, out);
}